// Round 1
// 203.894 us; speedup vs baseline: 1.0549x; 1.0549x over previous
//
#include <hip/hip_runtime.h>
#include <hip/hip_bf16.h>

#define BATCH 32
#define MAXPV 50
#define RN 256
#define PN 256
#define DIM 128
#define NI (BATCH*MAXPV)   // 1600 (b,pv) pairs

typedef unsigned short u16;
typedef __attribute__((ext_vector_type(8))) short short8;
typedef __attribute__((ext_vector_type(4))) float f32x4;

// ---- intermediates in the code object ----
__device__ float g_pa[NI*DIM], g_pb[NI*DIM], g_pc[NI*DIM];
__device__ float g_pp1[PN*DIM];
__device__ float g_raT[DIM*RN], g_rbT[DIM*RN];       // transposed [k][r]
__device__ float g_rmask[RN], g_regp[RN];
__device__ float g_scores[(size_t)NI*RN];            // per-(i,r) contribution (pad rows only valid)
__device__ short8 g_bfrag[8][4][64];                 // fc6 B-frags [nt][ks][lane]
__device__ float g_rcA[16*4*64*8];                   // rc in MFMA-A layout [mt][ks][lane][8]

__device__ __forceinline__ float bf2f(u16 u){ return __uint_as_float(((unsigned)u)<<16); }
__device__ __forceinline__ float LD(const void* p, size_t i, bool bf){
    return bf ? bf2f(((const u16*)p)[i]) : ((const float*)p)[i];
}
__device__ __forceinline__ int LDI(const void* p, size_t i, bool w64){
    return w64 ? (int)((const long long*)p)[i] : ((const int*)p)[i];
}
__device__ __forceinline__ short f2bf(float f){
    unsigned u = __float_as_uint(f);
    u = (u + 0x7FFFu + ((u>>16)&1u)) >> 16;
    return (short)u;
}
__device__ __forceinline__ unsigned f2bf2(float x, float y){
    float2 f; f.x=x; f.y=y;
    __hip_bfloat162 h = __float22bfloat162_rn(f);      // v_cvt_pk_bf16_f32
    union { __hip_bfloat162 h; unsigned u; } c; c.h=h; return c.u;
}
// ---- per-block inline dtype detection (wave-uniform, ~6 insts) ----
__device__ __forceinline__ bool det_bf16(const void* ent){
    int l = threadIdx.x & 63;
    u16 v = ((const u16*)ent)[(size_t)2*(l*4)*977];    // max idx 492,408: safe both dtypes
    int e = (v>>7)&0xFF;
    return __popcll(__ballot(e>=120 && e<=133)) >= 48; // bf16 ~64/64, fp32 ~6/64
}
__device__ __forceinline__ bool det_i64(const void* prop){
    int l = threadIdx.x & 63;
    bool z = (l<32) ? (((const unsigned*)prop)[2*l+1]==0u) : false;
    return __popcll(__ballot(z)) >= 30;                // int64: 32/32 odd words zero
}
__device__ __forceinline__ float wred(float v){
#pragma unroll
    for(int o=32;o;o>>=1) v += __shfl_xor(v,o,64);
    return v;
}
__device__ __forceinline__ double wredd(double v){
#pragma unroll
    for(int o=32;o;o>>=1) v += __shfl_xor(v,o,64);
    return v;
}
__device__ __forceinline__ float wmax(float v){
#pragma unroll
    for(int o=32;o;o>>=1) v = fmaxf(v,__shfl_xor(v,o,64));
    return v;
}

// ---------------- A: fused gather+l2norm+row-matmuls (replaces K1+K2) ----------------
// [0,100) pa | [100,200) pb | [200,300) pc | [300,316) raT | [316,332) rbT
// [332,348) rcA | [348,364) pp1 | [364,372) bfrag pack (+init on nt==0)
__global__ __launch_bounds__(256) void k_pre(
    const void* __restrict__ ent, const void* __restrict__ rule,
    const void* __restrict__ prop, const void* __restrict__ fc6w,
    const void* __restrict__ fc1w, const void* __restrict__ fc2w, const void* __restrict__ fc3w,
    const void* __restrict__ fc1b, const void* __restrict__ fc2b, const void* __restrict__ fc3b){
    const bool bf = det_bf16(ent);
    const int blk = blockIdx.x, tid = threadIdx.x;
    if(blk >= 364){                                   // bfrag pack + accum init
        int nt = blk-364;
        int ks = tid>>6, lane = tid&63;
        int n = nt*16 + (lane&15);
        int k0 = ks*32 + (lane>>4)*8;
        short8 v;
#pragma unroll
        for(int j=0;j<8;j++) v[j] = f2bf(LD(fc6w,(size_t)(k0+j)*DIM + n, bf));
        g_bfrag[nt][ks][lane] = v;
        if(nt==0){ g_rmask[tid] = 1.f; g_regp[tid] = 0.f; }
        return;
    }
    __shared__ float s_w[64*DIM];       // 32 KB (k-half of weights, fp32)
    __shared__ float s_in[16*DIM];      // 8 KB (gathered + normalized rows)
    __shared__ float s_bias[DIM];
    const void* w; size_t woff=0; const void* bptr=nullptr;
    float* out=nullptr; int row0; int mode=0; int srcsel;
    if(blk < 300){
        int wsel = blk/100; row0 = (blk%100)*16; srcsel = 0;
        w   = (wsel==0)?fc1w:(wsel==1)?fc2w:fc3w;
        out = (wsel==0)?g_pa:(wsel==1)?g_pb:g_pc;
    } else if(blk < 348){
        int rblk = blk-300; int wsel = rblk>>4; row0 = (rblk&15)*16; srcsel = 1;
        w    = (wsel==0)?fc1w:(wsel==1)?fc2w:fc3w;
        bptr = (wsel==0)?fc1b:(wsel==1)?fc2b:fc3b;
        woff = DIM*DIM; mode = wsel+1;
    } else { row0=(blk-348)*16; w=fc1w; out=g_pp1; srcsel=2; }
    // gather + l2norm the 16 input rows straight into LDS (same ops as old K1)
    const bool w64 = (srcsel==0) ? det_i64(prop) : false;
    {
        const int l = tid & 63;
        for(int it=0; it<4; it++){
            int lr = it*4 + (tid>>6);
            int row = row0 + lr;
            const void* src; size_t off;
            if(srcsel==0){ src=ent;  off=(size_t)LDI(prop,row,w64)*DIM; }
            else if(srcsel==1){ src=rule; off=(size_t)row*DIM; }
            else { src=ent; off=(size_t)row*DIM; }
            float a = LD(src,off+l,bf), b = LD(src,off+l+64,bf);
            float n = fmaxf(sqrtf((float)wredd((double)a*a+(double)b*b)), 1e-12f);
            s_in[lr*DIM+l]=a/n; s_in[lr*DIM+l+64]=b/n;
        }
    }
    if(tid<DIM) s_bias[tid] = bptr ? LD(bptr,tid,bf) : 0.f;
    const int j = tid & 127;
    const int rb8 = (tid>>7)*8;
    double acc[8] = {0,0,0,0,0,0,0,0};
    for(int half=0; half<2; half++){
        __syncthreads();
        for(int t=tid; t<64*DIM; t+=256)
            s_w[t] = LD(w, woff + (size_t)(half*64 + (t>>7))*DIM + (t&127), bf);
        __syncthreads();
        for(int k=0;k<64;k++){
            float wk = s_w[k*DIM + j];
#pragma unroll
            for(int rr=0;rr<8;rr++)
                acc[rr] += (double)s_in[(rb8+rr)*DIM + half*64 + k]*(double)wk;
        }
    }
    const double bj = (double)s_bias[j];
#pragma unroll
    for(int rr=0;rr<8;rr++){
        const int row = row0 + rb8 + rr;
        const float vv = (float)(bj + acc[rr]);
        if(mode==0)      out[(size_t)row*DIM + j] = vv;
        else if(mode==1) g_raT[j*256 + row] = vv;
        else if(mode==2) g_rbT[j*256 + row] = vv;
        else {           // rcA scatter: row in [0,256), k=j
            int mt=row>>4, am=row&15, ks=j>>5, quad=(j>>3)&3, jj=j&7;
            g_rcA[((mt*4+ks)*64 + quad*16+am)*8 + jj] = vv;
        }
    }
}

// ---------------- B: fused gates + MFMA scoring (replaces K3+K4) ----------------
// [0,3200): (i,h) blocks; [3200,3264): pi/rmask/reg blocks
__global__ __launch_bounds__(256) void k_score(
    const void* __restrict__ ent, const void* __restrict__ prop, const void* __restrict__ val,
    const void* __restrict__ same, const void* __restrict__ pad,
    const void* __restrict__ fc4w, const void* __restrict__ fc4b,
    const void* __restrict__ fc5w, const void* __restrict__ fc5b,
    const void* __restrict__ fc6b){
    const int blk = blockIdx.x, tid = threadIdx.x;
    const bool bf = det_bf16(ent);
    if(blk >= NI*2){                                   // ---- pi reduction (old K3 typeB) ----
        __shared__ float s_a[4][DIM];
        __shared__ double s_pf4[DIM];
        const int i0 = (blk - NI*2)*4;
        if(tid<DIM) s_pf4[tid]=(double)LD(fc4w,tid,bf);
        for(int t=tid; t<4*DIM; t+=256){
            int ii=t>>7, k=t&127;
            s_a[ii][k] = g_pp1[(size_t)(i0+ii)*DIM+k];
        }
        __syncthreads();
        const int r = tid;
        double d[4]={0.0,0.0,0.0,0.0};
        for(int k=0;k<DIM;k++){
            float rav = g_raT[k*256+r];
            double f4k = s_pf4[k];
#pragma unroll
            for(int ii=0;ii<4;ii++)
                d[ii] += (double)fmaxf(s_a[ii][k]+rav,0.f)*f4k;
        }
        const double b4 = (double)LD(fc4b,0,bf);
        float mask_sum = 0.f, reg_sum = 0.f;
#pragma unroll
        for(int ii=0;ii<4;ii++){
            int p = i0 + ii;
            double sd = d[ii] + b4;
            float piv = 1.f/(1.f+expf(-(float)sd));
            if(sd > 0.0) mask_sum += piv;              // piv>0.5 <=> sd>0
            float eff = (p==r) ? piv : (1.f - piv);
            float wgt = (p==r) ? (float)RN : 1.f;
            reg_sum += -logf(eff + 1e-8f)*wgt;
        }
        atomicAdd(&g_rmask[r], mask_sum);
        atomicAdd(&g_regp[r], reg_sum);
        return;
    }
    const int i = blk >> 1, h = blk & 1;
    const bool w64 = det_i64(prop);
    if(LDI(pad,i,w64)!=1) return;
    const bool issame = (LDI(same,i,w64)==1);

    __shared__ float s_pa[DIM], s_pb[DIM], s_pc[DIM], s_v[DIM];
    __shared__ float s_f5[DIM];
    __shared__ double s_f4[DIM];
    __shared__ float2 s_s1p[DIM];
    __shared__ float s_st[128][4][2];      // 4 KB

    if(tid < DIM){                          // waves 0,1: stage rows + gate weights
        s_pa[tid] = g_pa[(size_t)i*DIM + tid];
        s_pb[tid] = g_pb[(size_t)i*DIM + tid];
        s_pc[tid] = g_pc[(size_t)i*DIM + tid];
        s_f4[tid] = (double)LD(fc4w,tid,bf);
        s_f5[tid] = LD(fc5w,tid,bf);
    } else if(tid < 192){                   // wave 2: gather + l2norm v-row (old K1 ops)
        const int l = tid - 128;
        size_t off = (size_t)LDI(val,i,w64)*DIM;
        float a = LD(ent,off+l,bf), b = LD(ent,off+l+64,bf);
        float n = fmaxf(sqrtf((float)wredd((double)a*a+(double)b*b)), 1e-12f);
        s_v[l]=a/n; s_v[l+64]=b/n;
    }
    __syncthreads();

    // ---- gate phase (old K3 typeA, in-block, same op order) ----
    if(tid < 128){
        const int r = h*128 + tid;
        double d = 0.0; float pq = 0.f;
        if(issame){
            for(int k=0;k<DIM;k++){
                float rav = g_raT[k*256+r];
                float rbv = g_rbT[k*256+r];
                d += (double)fmaxf(s_pa[k]+rav,0.f)*s_f4[k];
                pq = fmaf(fmaxf(s_pb[k]+rbv,0.f), s_f5[k], pq);
            }
        } else {
            for(int k=0;k<DIM;k++){
                float rav = g_raT[k*256+r];
                d += (double)fmaxf(s_pa[k]+rav,0.f)*s_f4[k];
            }
        }
        const double b4 = (double)LD(fc4b,0,bf);
        double sd = d + b4;
        float s1v = 1.f/(1.f+expf(-(float)sd));
        if(issame){
            const float b5 = LD(fc5b,0,bf);
            float p = 1.f/(1.f+expf(-(pq + b5)));
            float2 o; o.x = (sd > 0.0) ? s1v : -s1v; o.y = p;
            s_s1p[tid] = o;
        } else {
            g_scores[(size_t)i*RN + r] = (sd > 0.0) ? (1.f - s1v) : 0.f;
        }
    }
    if(!issame) return;
    __syncthreads();                        // s_s1p ready

    // ---- MFMA phase (old K4, verbatim; s_v/s_s1p instead of g_v/g_s1p) ----
    const int w = tid>>6, l = tid&63;
    const int am = l&15, quad = l>>4;
    short8 bA[4], bB[4];
#pragma unroll
    for(int ks=0; ks<4; ks++){ bA[ks]=g_bfrag[2*w][ks][l]; bB[ks]=g_bfrag[2*w+1][ks][l]; }
    const int n0 = w*32 + am, n1 = n0 + 16;
    const float v0 = s_v[n0], v1 = s_v[n1];
    const float b60 = LD(fc6b, n0, bf), b61 = LD(fc6b, n1, bf);
    float vl = s_v[l], vh = s_v[l+64];
    const float nvb = sqrtf(wred(vl*vl + vh*vh));

    int mt = h*8;
    float4 c[8];
#pragma unroll
    for(int ks=0; ks<4; ks++){
        const float* rp = &g_rcA[((mt*4+ks)*64 + l)*8];
        c[2*ks]   = *(const float4*)rp;
        c[2*ks+1] = *(const float4*)(rp+4);
    }
    for(int mtl=0; mtl<8; mtl++){
        float4 n[8];
        if(mtl < 7){
#pragma unroll
            for(int ks=0; ks<4; ks++){
                const float* rp = &g_rcA[(((mt+1)*4+ks)*64 + l)*8];
                n[2*ks]   = *(const float4*)rp;
                n[2*ks+1] = *(const float4*)(rp+4);
            }
        }
        short8 a[4];
#pragma unroll
        for(int ks=0; ks<4; ks++){
            const float4 p0 = *(const float4*)&s_pc[ks*32 + quad*8];
            const float4 p1 = *(const float4*)&s_pc[ks*32 + quad*8 + 4];
            const float4 c0 = c[2*ks], c1 = c[2*ks+1];
            union { short8 s; unsigned u[4]; } t;
            t.u[0] = f2bf2(fmaxf(p0.x+c0.x,0.f), fmaxf(p0.y+c0.y,0.f));
            t.u[1] = f2bf2(fmaxf(p0.z+c0.z,0.f), fmaxf(p0.w+c0.w,0.f));
            t.u[2] = f2bf2(fmaxf(p1.x+c1.x,0.f), fmaxf(p1.y+c1.y,0.f));
            t.u[3] = f2bf2(fmaxf(p1.z+c1.z,0.f), fmaxf(p1.w+c1.w,0.f));
            a[ks] = t.s;
        }
        f32x4 acc0 = {0.f,0.f,0.f,0.f}, acc1 = {0.f,0.f,0.f,0.f};
#pragma unroll
        for(int ks=0; ks<4; ks++){
            acc0 = __builtin_amdgcn_mfma_f32_16x16x32_bf16(a[ks], bA[ks], acc0, 0,0,0);
            acc1 = __builtin_amdgcn_mfma_f32_16x16x32_bf16(a[ks], bB[ks], acc1, 0,0,0);
        }
#pragma unroll
        for(int q=0; q<4; q++){
            float x0 = acc0[q] + b60;
            float x1 = acc1[q] + b61;
            float ss = x0*x0 + x1*x1;
            float dv = x0*v0 + x1*v1;
#pragma unroll
            for(int o=1;o<16;o<<=1){ ss += __shfl_xor(ss,o,64); dv += __shfl_xor(dv,o,64); }
            if(am==0){
                int row = mtl*16 + quad*4 + q;
                s_st[row][w][0] = ss;
                s_st[row][w][1] = dv;
            }
        }
#pragma unroll
        for(int x=0;x<8;x++) c[x] = n[x];
        mt++;
    }
    __syncthreads();
    if(tid < 128){
        const int r = h*128 + tid;
        float ss = s_st[tid][0][0]+s_st[tid][1][0]+s_st[tid][2][0]+s_st[tid][3][0];
        float dv = s_st[tid][0][1]+s_st[tid][1][1]+s_st[tid][2][1]+s_st[tid][3][1];
        float2 sp = s_s1p[tid];
        float s1 = fabsf(sp.x);
        float gate = (sp.x > 0.f) ? 1.f : 0.f;
        float pp = sp.y;
        float nx = sqrtf(ss);
        float clipnx = fmaxf(nx, 1e-12f);
        float gvn = nx/clipnx;
        float denom = fmaxf(nvb*gvn, 1e-8f);
        float cosv = (dv/clipnx)/denom;
        float s2 = 0.5f*cosv + 0.5f;
        float sc = s1*(pp + (1.f-pp)*s2);
        g_scores[(size_t)i*RN + r] = sc * gate;
    }
}

// ---------------- C: pooled max + reg mean ----------------
__global__ void k_fin(float* __restrict__ out, const void* __restrict__ prop,
                      const void* __restrict__ same, const void* __restrict__ pad){
    const bool w64 = det_i64(prop);
    const int blk = blockIdx.x, tid = threadIdx.x;
    const int w = tid>>6, l = tid&63;
    __shared__ float s[4];
    if(blk < 32){
        __shared__ int s_pad[MAXPV];
        if(tid < MAXPV) s_pad[tid] = LDI(pad, (size_t)blk*MAXPV + tid, w64);
        __syncthreads();
        float ssum = 0.f;
        for(int pv=0; pv<MAXPV; pv++){
            if(!s_pad[pv]) continue;
            ssum += g_scores[((size_t)blk*MAXPV + pv)*RN + tid];
        }
        float sc = ssum / g_rmask[tid];
        float m = wmax(sc);
        if(l==0) s[w]=m;
        __syncthreads();
        if(tid==0) out[blk] = fmaxf(fmaxf(s[0],s[1]), fmaxf(s[2],s[3]));
    } else {
        float v = g_regp[tid];
        v = wred(v);
        if(l==0) s[w]=v;
        __syncthreads();
        if(tid==0) out[32] = (s[0]+s[1]+s[2]+s[3]) / (float)(RN*PN);
    }
}

extern "C" void kernel_launch(void* const* d_in, const int* in_sizes, int n_in,
                              void* d_out, int out_size, void* d_ws, size_t ws_size,
                              hipStream_t stream){
    int map[18]; for(int i=0;i<18;i++) map[i]=i;
    if(n_in>=18 && in_sizes[0]==6400000){
        const int a[18] = {14,17,16,13,15,0,2,1,4,3,6,5,8,7,10,9,12,11};
        for(int i=0;i<18;i++) map[i]=a[i];
    }
    const void* prop = d_in[map[0]];
    const void* val  = d_in[map[1]];
    const void* same = d_in[map[2]];
    const void* pad  = d_in[map[3]];
    const void* rule = d_in[map[4]];
    const void* ent  = d_in[map[5]];
    const void* fc1w = d_in[map[6]];
    const void* fc1b = d_in[map[7]];
    const void* fc2w = d_in[map[8]];
    const void* fc2b = d_in[map[9]];
    const void* fc3w = d_in[map[10]];
    const void* fc3b = d_in[map[11]];
    const void* fc4w = d_in[map[12]];
    const void* fc4b = d_in[map[13]];
    const void* fc5w = d_in[map[14]];
    const void* fc5b = d_in[map[15]];
    const void* fc6w = d_in[map[16]];
    const void* fc6b = d_in[map[17]];

    k_pre<<<372, 256, 0, stream>>>(ent, rule, prop, fc6w,
                                   fc1w, fc2w, fc3w, fc1b, fc2b, fc3b);
    k_score<<<NI*2+64, 256, 0, stream>>>(ent, prop, val, same, pad,
                                         fc4w, fc4b, fc5w, fc5b, fc6b);
    k_fin<<<33, 256, 0, stream>>>((float*)d_out, prop, same, pad);
}